// Round 3
// baseline (2064.271 us; speedup 1.0000x reference)
//
#include <hip/hip_runtime.h>

// cluster_layer: q[n,k] = (1/(1+||x_n - c_k||^2)) normalized over k  (alpha=1)
// N=1e6, D=64, K=20. HBM floor: 256 MB read + 80 MB write ~ 53 us (less w/ L3).
//
// R3: per-lane contiguous 128 B x-chunks (R2's fetch win: 166 MB) + clusters
// staged ONCE per block into LDS, transposed [jc][k] float4, uniform
// ds_read_b128 broadcast amortized over RPT=4 rows/thread (fixes R2's
// per-thread cluster re-read bottleneck: 320 ds/wave * 15.3 waves/CU * 12cyc
// ~ 24 us < HBM floor).

#define NPTS 1000000
#define DIM  64
#define KCL  20
#define BLOCK 256
#define RPT  4            // rows per thread
#define MC   8            // float4 per chunk = 128 B (full cache line per row)
#define NCH  (DIM / 4 / MC)  // 2 chunks

__global__ __launch_bounds__(BLOCK, 2) void cluster_q_kernel(
    const float* __restrict__ x,
    const float* __restrict__ c,
    float* __restrict__ out)
{
    __shared__ float4 sC4[DIM / 4][KCL];   // transposed: [jc][k]
    __shared__ float  sCsq[KCL];

    // stage clusters (one-time, 5 KB)
    const int tid = threadIdx.x;
    for (int i = tid; i < KCL * (DIM / 4); i += BLOCK) {
        int k  = i / (DIM / 4);
        int jc = i % (DIM / 4);
        sC4[jc][k] = ((const float4*)c)[k * (DIM / 4) + jc];
    }
    __syncthreads();
    if (tid < KCL) {
        float s = 0.f;
        #pragma unroll
        for (int jc = 0; jc < DIM / 4; ++jc) {
            float4 v = sC4[jc][tid];
            s += v.x * v.x + v.y * v.y + v.z * v.z + v.w * v.w;
        }
        sCsq[tid] = s;
    }
    __syncthreads();

    int  row[RPT];
    bool valid[RPT];
    #pragma unroll
    for (int r = 0; r < RPT; ++r) {
        int rr = blockIdx.x * (BLOCK * RPT) + r * BLOCK + tid;
        valid[r] = (rr < NPTS);
        row[r] = valid[r] ? rr : (NPTS - 1);   // clamped duplicate load is harmless
    }

    float acc[RPT][KCL];
    float xsq[RPT];
    #pragma unroll
    for (int r = 0; r < RPT; ++r) {
        xsq[r] = 0.f;
        #pragma unroll
        for (int k = 0; k < KCL; ++k) acc[r][k] = 0.f;
    }

    const float4* __restrict__ x4 = (const float4*)x;

    #pragma unroll
    for (int ch = 0; ch < NCH; ++ch) {
        // load 128 B per row, back-to-back dwordx4 (line fully consumed)
        float4 xv[RPT][MC];
        #pragma unroll
        for (int r = 0; r < RPT; ++r)
            #pragma unroll
            for (int mc = 0; mc < MC; ++mc)
                xv[r][mc] = x4[(size_t)row[r] * (DIM / 4) + ch * MC + mc];

        #pragma unroll
        for (int r = 0; r < RPT; ++r)
            #pragma unroll
            for (int mc = 0; mc < MC; ++mc)
                xsq[r] += xv[r][mc].x * xv[r][mc].x + xv[r][mc].y * xv[r][mc].y
                        + xv[r][mc].z * xv[r][mc].z + xv[r][mc].w * xv[r][mc].w;

        #pragma unroll
        for (int mc = 0; mc < MC; ++mc) {
            const int jc = ch * MC + mc;
            #pragma unroll
            for (int k = 0; k < KCL; ++k) {
                const float4 cv = sC4[jc][k];   // uniform addr -> LDS broadcast
                #pragma unroll
                for (int r = 0; r < RPT; ++r)
                    acc[r][k] += xv[r][mc].x * cv.x + xv[r][mc].y * cv.y
                               + xv[r][mc].z * cv.z + xv[r][mc].w * cv.w;
            }
        }
    }

    // epilogue: d2 -> q -> normalize -> 5 aligned float4 stores per row
    #pragma unroll
    for (int r = 0; r < RPT; ++r) {
        if (!valid[r]) continue;
        float s = 0.f;
        float q[KCL];
        #pragma unroll
        for (int k = 0; k < KCL; ++k) {
            float d2 = xsq[r] + sCsq[k] - 2.0f * acc[r][k];
            float qq = __builtin_amdgcn_rcpf(1.0f + d2);   // v_rcp_f32, ~1 ulp
            q[k] = qq;
            s += qq;
        }
        const float inv = __builtin_amdgcn_rcpf(s);
        float4* o4 = (float4*)(out + (size_t)row[r] * KCL);
        #pragma unroll
        for (int k = 0; k < KCL; k += 4) {
            float4 v;
            v.x = q[k + 0] * inv;
            v.y = q[k + 1] * inv;
            v.z = q[k + 2] * inv;
            v.w = q[k + 3] * inv;
            o4[k / 4] = v;
        }
    }
}

extern "C" void kernel_launch(void* const* d_in, const int* in_sizes, int n_in,
                              void* d_out, int out_size, void* d_ws, size_t ws_size,
                              hipStream_t stream) {
    const float* x = (const float*)d_in[0];   // (N, D) fp32
    const float* c = (const float*)d_in[1];   // (K, D) fp32
    float* out = (float*)d_out;               // (N, K) fp32

    const int rows_per_block = BLOCK * RPT;                          // 1024
    const int blocks = (NPTS + rows_per_block - 1) / rows_per_block; // 977
    cluster_q_kernel<<<blocks, BLOCK, 0, stream>>>(x, c, out);
}